// Round 5
// baseline (1296.043 us; speedup 1.0000x reference)
//
#include <hip/hip_runtime.h>
#include <hip/hip_bf16.h>
#include <stdint.h>

// Fused gather + (ep-eq)^2 + MLP(256->256->256->1) for MI355X (gfx950).
//
// Round 5: producer/consumer wave specialization.
//  R4 failed: 64 short8 weight frags = 256 VGPRs -> scratch spill disaster
//  (WRITE_SIZE 167 MB). Also, in-order vmcnt means register-prefetched
//  gathers would stall any younger B-fragment load -> register pipelining
//  of the gather cannot work in one wave.
//  Fix: waves 0-3 = PRODUCERS (gather tile t+1, sqdiff, LDS commit),
//       waves 4-7 = CONSUMERS (GEMM1 -> ep1 -> GEMM2 -> ep2 on tile t).
//  Separate waves = separate vmcnt counters: gather latency hidden under
//  ~10k cycles of MFMA. MT=128 double-buffered (2x64 KB + 2 KB = 133120 B,
//  R1's exact proven LDS size) -> 1 block/CU, grid=256 persistent.
//  Consumer: 128x64 wave tile, acc[8][4] (128 AGPR), B depth-2 from L2
//  (32 VGPR, self-owned vmcnt). ~240 unified regs, launch_bounds(512,2).

#define D 256
#define MT 128
#define THREADS 512
#define PGRID 256

typedef __attribute__((ext_vector_type(8))) short short8;
typedef __attribute__((ext_vector_type(4))) float f32x4;

// bf16 round-to-nearest-even
__device__ __forceinline__ unsigned short f2bf(float f) {
    unsigned int u = __float_as_uint(f);
    unsigned int r = (u + 0x7FFFu + ((u >> 16) & 1u)) >> 16;
    return (unsigned short)r;
}
__device__ __forceinline__ float bflo(unsigned int u) { return __uint_as_float(u << 16); }
__device__ __forceinline__ float bfhi(unsigned int u) { return __uint_as_float(u & 0xFFFF0000u); }

__device__ __forceinline__ unsigned int sqdiff2(unsigned int p, unsigned int q) {
    float d0 = bflo(p) - bflo(q);
    float d1 = bfhi(p) - bfhi(q);
    return (unsigned int)f2bf(d0 * d0) | ((unsigned int)f2bf(d1 * d1) << 16);
}

// ---------------- embedding fp32 -> bf16 table ----------------
__global__ void conv_emb_kernel(const float* __restrict__ in,
                                unsigned short* __restrict__ out, int nchunks) {
    int i = blockIdx.x * blockDim.x + threadIdx.x;
    if (i >= nchunks) return;
    const float4* p = reinterpret_cast<const float4*>(in) + 2 * (size_t)i;
    float4 a = p[0], b = p[1];
    uint4 o;
    o.x = (unsigned int)f2bf(a.x) | ((unsigned int)f2bf(a.y) << 16);
    o.y = (unsigned int)f2bf(a.z) | ((unsigned int)f2bf(a.w) << 16);
    o.z = (unsigned int)f2bf(b.x) | ((unsigned int)f2bf(b.y) << 16);
    o.w = (unsigned int)f2bf(b.z) | ((unsigned int)f2bf(b.w) << 16);
    reinterpret_cast<uint4*>(out)[i] = o;
}

// ---------------- weight packing ----------------
// Pack W (row-major fp32 [K=256][N=256]) into bf16 B-fragments for
// v_mfma_f32_16x16x32_bf16. Fragment (nt, ks): lane L holds
//   B[k = ks*32 + (L>>4)*8 + j][n = nt*16 + (L&15)], j = 0..7
__global__ void pack_w_kernel(const float* __restrict__ w1,
                              const float* __restrict__ w2,
                              unsigned short* __restrict__ out) {
    int tid = blockIdx.x * blockDim.x + threadIdx.x;   // 0..16383
    int mat = tid >> 13;
    const float* W = mat ? w2 : w1;
    unsigned short* o = out + mat * 65536;
    int rem  = tid & 8191;
    int nt   = rem >> 9;
    int ks   = (rem >> 6) & 7;
    int lane = rem & 63;
    int kbase = ks * 32 + (lane >> 4) * 8;
    int n     = nt * 16 + (lane & 15);
    short8 v;
#pragma unroll
    for (int j = 0; j < 8; ++j)
        v[j] = (short)f2bf(W[(kbase + j) * 256 + n]);
    *reinterpret_cast<short8*>(o + (((nt * 8) + ks) * 64 + lane) * 8) = v;
}

// ---------------- fused main kernel (producer/consumer waves) --------------
template <bool BF16T>
__launch_bounds__(THREADS, 2)
__global__ void fused_kernel(const int* __restrict__ pv,
                             const int* __restrict__ qv,
                             const float* __restrict__ embf,
                             const unsigned short* __restrict__ embb,
                             const float* __restrict__ b1,
                             const float* __restrict__ b2,
                             const float* __restrict__ w3,
                             const float* __restrict__ b3,
                             const unsigned short* __restrict__ wpack,
                             float* __restrict__ out,
                             int M, int nblk) {
    // double-buffered A/H tile; row stride 512 B, XOR-swizzled 16 B units
    __shared__ unsigned char lds_buf[2][MT * 512];
    __shared__ float lds_part[4][MT];

    const int tid    = threadIdx.x;
    const int lane   = tid & 63;
    const int wave   = tid >> 6;         // 0..7
    const int stride = gridDim.x;

    if (wave < 4) {
        // ======================= PRODUCER waves =======================
        const int rr = lane >> 5;        // half-wave row offset
        const int cc = lane & 31;        // 16 B unit within row
        const int rowbase = wave * 32;   // 32 rows per producer wave
        const float b3v = b3[0];

        auto fill = [&](int t, unsigned char* buf) {
            if (BF16T) {
#pragma unroll
                for (int half = 0; half < 2; ++half) {
                    uint4 ga[8], gb[8];
                    int rbeg = rowbase + half * 16;
#pragma unroll
                    for (int it = 0; it < 8; ++it) {
                        int r  = rbeg + it * 2 + rr;
                        int gi = t * MT + r;
                        int pi = 0, qi = 0;
                        if (gi < M) { pi = pv[gi]; qi = qv[gi]; }
                        ga[it] = *(reinterpret_cast<const uint4*>(embb + (size_t)pi * D) + cc);
                        gb[it] = *(reinterpret_cast<const uint4*>(embb + (size_t)qi * D) + cc);
                    }
#pragma unroll
                    for (int it = 0; it < 8; ++it) {
                        int r = rbeg + it * 2 + rr;
                        uint4 o;
                        o.x = sqdiff2(ga[it].x, gb[it].x);
                        o.y = sqdiff2(ga[it].y, gb[it].y);
                        o.z = sqdiff2(ga[it].z, gb[it].z);
                        o.w = sqdiff2(ga[it].w, gb[it].w);
                        unsigned int unit = (unsigned int)cc ^ (unsigned int)(r & 31);
                        *reinterpret_cast<uint4*>(&buf[(unsigned int)r * 512u + (unit << 4)]) = o;
                    }
                }
            } else {
#pragma unroll
                for (int it = 0; it < 16; ++it) {
                    int r  = rowbase + it * 2 + rr;
                    int gi = t * MT + r;
                    int pi = 0, qi = 0;
                    if (gi < M) { pi = pv[gi]; qi = qv[gi]; }
                    const float4* ep = reinterpret_cast<const float4*>(embf + (size_t)pi * D) + cc * 2;
                    const float4* eq = reinterpret_cast<const float4*>(embf + (size_t)qi * D) + cc * 2;
                    float4 a0 = ep[0], a1 = ep[1], q0 = eq[0], q1 = eq[1];
                    float d0 = a0.x - q0.x, d1 = a0.y - q0.y, d2 = a0.z - q0.z, d3 = a0.w - q0.w;
                    float d4 = a1.x - q1.x, d5 = a1.y - q1.y, d6 = a1.z - q1.z, d7 = a1.w - q1.w;
                    uint4 o;
                    o.x = (unsigned int)f2bf(d0 * d0) | ((unsigned int)f2bf(d1 * d1) << 16);
                    o.y = (unsigned int)f2bf(d2 * d2) | ((unsigned int)f2bf(d3 * d3) << 16);
                    o.z = (unsigned int)f2bf(d4 * d4) | ((unsigned int)f2bf(d5 * d5) << 16);
                    o.w = (unsigned int)f2bf(d6 * d6) | ((unsigned int)f2bf(d7 * d7) << 16);
                    unsigned int unit = (unsigned int)cc ^ (unsigned int)(r & 31);
                    *reinterpret_cast<uint4*>(&buf[(unsigned int)r * 512u + (unit << 4)]) = o;
                }
            }
        };

        // prologue: fill buf0 with this block's first tile
        fill(blockIdx.x, lds_buf[0]);
        __syncthreads();                               // P: A(t0) ready

        int cur = 0;
        for (int t = blockIdx.x; t < nblk; t += stride) {
            int tn = t + stride;
            if (tn < nblk) fill(tn, lds_buf[cur ^ 1]); // overlaps consumer GEMM1
            __syncthreads();                           // B1
            __syncthreads();                           // B2
            __syncthreads();                           // B3: partials + next A ready
            if (tid < MT) {
                int gi = t * MT + tid;
                if (gi < M)
                    out[gi] = lds_part[0][tid] + lds_part[1][tid] +
                              lds_part[2][tid] + lds_part[3][tid] + b3v;
            }
            cur ^= 1;
        }
    } else {
        // ======================= CONSUMER waves =======================
        const int wc    = wave - 4;      // n-quarter 0..3
        const int nbase = wc * 64;
        const int l15   = lane & 15;
        const int quad  = lane >> 4;

        const short8* wp1 = reinterpret_cast<const short8*>(wpack);
        const short8* wp2 = wp1 + 8192;

        float b1v[4], b2v[4], w3v[4];
#pragma unroll
        for (int ct = 0; ct < 4; ++ct) {
            int c = nbase + ct * 16 + l15;
            b1v[ct] = b1[c];
            b2v[ct] = b2[c];
            w3v[ct] = w3[c];
        }

        f32x4 acc[8][4];

#define LOADB(buf, wp, ksv)                                            \
    _Pragma("unroll")                                                  \
    for (int ct = 0; ct < 4; ++ct)                                     \
        buf[ct] = (wp)[((((nbase >> 4) + ct) * 8) + (ksv)) * 64 + lane];

#define MFMA32(bu)                                                      \
    _Pragma("unroll")                                                   \
    for (int mt = 0; mt < 8; ++mt)                                      \
        _Pragma("unroll")                                               \
        for (int ct = 0; ct < 4; ++ct)                                  \
            acc[mt][ct] = __builtin_amdgcn_mfma_f32_16x16x32_bf16(      \
                af[mt], bu[ct], acc[mt][ct], 0, 0, 0);

        auto gemm = [&](const short8* wp, const unsigned char* buf) {
#pragma unroll
            for (int mt = 0; mt < 8; ++mt)
#pragma unroll
                for (int ct = 0; ct < 4; ++ct)
                    acc[mt][ct] = (f32x4){0.f, 0.f, 0.f, 0.f};
            short8 bb0[4], bb1[4];
            LOADB(bb0, wp, 0)
            LOADB(bb1, wp, 1)
#pragma unroll
            for (int ks = 0; ks < 8; ++ks) {
                short8 af[8];
#pragma unroll
                for (int mt = 0; mt < 8; ++mt) {
                    int r = mt * 16 + l15;
                    unsigned int unit = (unsigned int)(ks * 4 + quad) ^ (unsigned int)(r & 31);
                    af[mt] = *reinterpret_cast<const short8*>(
                        &buf[(unsigned int)r * 512u + (unit << 4)]);
                }
                if (ks & 1) {
                    MFMA32(bb1)
                    if (ks < 6) LOADB(bb1, wp, ks + 2)
                } else {
                    MFMA32(bb0)
                    if (ks < 6) LOADB(bb0, wp, ks + 2)
                }
            }
        };

        __syncthreads();                               // P: A(t0) ready

        int cur = 0;
        for (int t = blockIdx.x; t < nblk; t += stride) {
            // ---- GEMM1 ----
            gemm(wp1, lds_buf[cur]);
            __syncthreads();                           // B1: A reads done

            // ---- ep1: +b1, relu, bf16 -> H in same buffer ----
#pragma unroll
            for (int ct = 0; ct < 4; ++ct) {
                int c = nbase + ct * 16 + l15;
#pragma unroll
                for (int mt = 0; mt < 8; ++mt)
#pragma unroll
                    for (int j = 0; j < 4; ++j) {
                        float v = fmaxf(acc[mt][ct][j] + b1v[ct], 0.f);
                        int r = mt * 16 + quad * 4 + j;
                        unsigned int unit = (unsigned int)(c >> 3) ^ (unsigned int)(r & 31);
                        unsigned int addr = (unsigned int)r * 512u + (unit << 4)
                                          + (unsigned int)(c & 7) * 2u;
                        *reinterpret_cast<unsigned short*>(&lds_buf[cur][addr]) = f2bf(v);
                    }
            }
            __syncthreads();                           // B2: H visible

            // ---- GEMM2 + fused w3 dot ----
            gemm(wp2, lds_buf[cur]);

            float part[8][4];
#pragma unroll
            for (int mt = 0; mt < 8; ++mt)
#pragma unroll
                for (int j = 0; j < 4; ++j)
                    part[mt][j] = 0.f;
#pragma unroll
            for (int ct = 0; ct < 4; ++ct)
#pragma unroll
                for (int mt = 0; mt < 8; ++mt)
#pragma unroll
                    for (int j = 0; j < 4; ++j) {
                        float v = fmaxf(acc[mt][ct][j] + b2v[ct], 0.f);
                        part[mt][j] += v * w3v[ct];
                    }
#pragma unroll
            for (int msk = 8; msk >= 1; msk >>= 1)
#pragma unroll
                for (int mt = 0; mt < 8; ++mt)
#pragma unroll
                    for (int j = 0; j < 4; ++j)
                        part[mt][j] += __shfl_xor(part[mt][j], msk, 64);
            if (l15 == 0) {
#pragma unroll
                for (int mt = 0; mt < 8; ++mt)
#pragma unroll
                    for (int j = 0; j < 4; ++j)
                        lds_part[wc][mt * 16 + quad * 4 + j] = part[mt][j];
            }
            __syncthreads();                           // B3
            cur ^= 1;
        }
#undef LOADB
#undef MFMA32
    }
}

extern "C" void kernel_launch(void* const* d_in, const int* in_sizes, int n_in,
                              void* d_out, int out_size, void* d_ws, size_t ws_size,
                              hipStream_t stream) {
    const int*   pv  = (const int*)d_in[0];
    const int*   qv  = (const int*)d_in[1];
    const float* emb = (const float*)d_in[2];
    const float* w1  = (const float*)d_in[3];
    const float* b1  = (const float*)d_in[4];
    const float* w2  = (const float*)d_in[5];
    const float* b2  = (const float*)d_in[6];
    const float* w3  = (const float*)d_in[7];
    const float* b3  = (const float*)d_in[8];
    float* out = (float*)d_out;
    const int M  = in_sizes[0];
    const int NV = in_sizes[2] / D;

    const size_t tbl_bytes   = (size_t)NV * D * sizeof(unsigned short); // 102.4 MB
    const size_t wpack_bytes = 2u * 65536u * sizeof(unsigned short);    // 256 KB
    const bool use_bf16 = (ws_size >= tbl_bytes + wpack_bytes);         // launch-constant

    unsigned short* table = (unsigned short*)d_ws;
    unsigned short* wpack = use_bf16
        ? (unsigned short*)((char*)d_ws + tbl_bytes)
        : (unsigned short*)d_ws;

    pack_w_kernel<<<32, 512, 0, stream>>>(w1, w2, wpack);

    const int nblk = (M + MT - 1) / MT;
    const int grid = nblk < PGRID ? nblk : PGRID;
    if (use_bf16) {
        int nch = (int)((size_t)NV * D / 8);
        conv_emb_kernel<<<(nch + 255) / 256, 256, 0, stream>>>(emb, table, nch);
        fused_kernel<true><<<grid, THREADS, 0, stream>>>(
            pv, qv, emb, table, b1, b2, w3, b3, wpack, out, M, nblk);
    } else {
        fused_kernel<false><<<grid, THREADS, 0, stream>>>(
            pv, qv, emb, nullptr, b1, b2, w3, b3, wpack, out, M, nblk);
    }
}